// Round 3
// baseline (5523.157 us; speedup 1.0000x reference)
//
#include <hip/hip_runtime.h>

typedef unsigned short u16;
typedef unsigned int u32;

#define T_SEQ 2048
#define NHEAD 16
#define HDIM 64
#define CDIM 1024

// Octonion sign table: SG[a][n] = sign of component (a^n) of e_a * e_n.
// Byte a of SGBITS holds row a; bit n set => negative.
// Triple-verified entry-by-entry from Cayley-Dickson (a,b)(c,d)=(ac-d~b, da+bc~),
// Hamilton quaternions i*j=k; matches reference qmul/omul exactly.
#define SGBITS 0xB2D8741EACC66A00ULL

// C[i,n] = sum_c A[i,c] * B[n,c]  (A: MxK fp32, B: NxK fp32, C: MxN fp32)
__global__ __launch_bounds__(256) void gemm_ff_f(const float* __restrict__ A, const float* __restrict__ B,
                                                 float* __restrict__ C, int M, int N, int K) {
    __shared__ float As[16][132];
    __shared__ float Bs[16][68];
    int tid = threadIdx.x;
    int bm = blockIdx.y * 128, bn = blockIdx.x * 64;
    int alr = tid >> 1, alc = (tid & 1) * 8;
    int blr = tid >> 2, blc = (tid & 3) * 4;
    const float* Ap = A + (size_t)(bm + alr) * K + alc;
    const float* Bp = B + (size_t)(bn + blr) * K + blc;
    int tx = tid & 15, ty = tid >> 4;
    float acc[8][4];
#pragma unroll
    for (int i = 0; i < 8; ++i)
#pragma unroll
        for (int j = 0; j < 4; ++j) acc[i][j] = 0.f;
    for (int k0 = 0; k0 < K; k0 += 16) {
        float4 a0 = *(const float4*)(Ap + k0);
        float4 a1 = *(const float4*)(Ap + k0 + 4);
        float4 b0 = *(const float4*)(Bp + k0);
        __syncthreads();
        As[alc + 0][alr] = a0.x; As[alc + 1][alr] = a0.y;
        As[alc + 2][alr] = a0.z; As[alc + 3][alr] = a0.w;
        As[alc + 4][alr] = a1.x; As[alc + 5][alr] = a1.y;
        As[alc + 6][alr] = a1.z; As[alc + 7][alr] = a1.w;
        Bs[blc + 0][blr] = b0.x; Bs[blc + 1][blr] = b0.y;
        Bs[blc + 2][blr] = b0.z; Bs[blc + 3][blr] = b0.w;
        __syncthreads();
#pragma unroll
        for (int kk = 0; kk < 16; ++kk) {
            float av[8], bv[4];
#pragma unroll
            for (int u = 0; u < 8; ++u) av[u] = As[kk][ty * 8 + u];
#pragma unroll
            for (int u = 0; u < 4; ++u) bv[u] = Bs[kk][tx * 4 + u];
#pragma unroll
            for (int uy = 0; uy < 8; ++uy)
#pragma unroll
                for (int ux = 0; ux < 4; ++ux) acc[uy][ux] = fmaf(av[uy], bv[ux], acc[uy][ux]);
        }
    }
#pragma unroll
    for (int uy = 0; uy < 8; ++uy) {
        float4 o = make_float4(acc[uy][0], acc[uy][1], acc[uy][2], acc[uy][3]);
        *(float4*)(C + (size_t)(bm + ty * 8 + uy) * N + bn + tx * 4) = o;
    }
}

// One wave per (t, h): rotary -> RMS norm for q and k; octonion-normalized conjugated k -> kc.
__global__ __launch_bounds__(256) void prep_rope(float* __restrict__ q, float* __restrict__ k,
                                                 float* __restrict__ kc,
                                                 const float* __restrict__ cosb, const float* __restrict__ sinb) {
    int wave = threadIdx.x >> 6, lane = threadIdx.x & 63;
    int idx = blockIdx.x * 4 + wave;
    int t = idx >> 4, h = idx & 15;
    int d = lane & 31;
    float cs = cosb[t * 32 + d];
    float sn = sinb[t * 32 + d];
    size_t base = (size_t)t * CDIM + h * HDIM;

    float xq = q[base + lane];
    float oq = __shfl(xq, lane ^ 32);
    float rq = (lane < 32) ? fmaf(xq, cs, oq * sn) : fmaf(xq, cs, -oq * sn);
    float ssq = rq * rq;
#pragma unroll
    for (int m = 1; m < 64; m <<= 1) ssq += __shfl_xor(ssq, m);
    rq *= rsqrtf(ssq * (1.f / 64.f) + 1e-6f);
    q[base + lane] = rq;

    float xk = k[base + lane];
    float ok = __shfl(xk, lane ^ 32);
    float rk = (lane < 32) ? fmaf(xk, cs, ok * sn) : fmaf(xk, cs, -ok * sn);
    float ssk = rk * rk;
#pragma unroll
    for (int m = 1; m < 64; m <<= 1) ssk += __shfl_xor(ssk, m);
    rk *= rsqrtf(ssk * (1.f / 64.f) + 1e-6f);
    k[base + lane] = rk;

    float s8 = rk * rk;
    s8 += __shfl_xor(s8, 1); s8 += __shfl_xor(s8, 2); s8 += __shfl_xor(s8, 4);
    float sc2 = 1.f / fmaxf(sqrtf(s8), 1e-12f);
    float kcv = rk * sc2;
    if (lane & 7) kcv = -kcv;  // octonion conjugate: negate components 1..7
    kc[base + lane] = kcv;
}

// One wave per (h, i): online-softmax causal attention with pairwise octonion values.
// Lane l owns output element (m = l>>3, e = l&7). Uses idx(e_a o e_b)=a^b + SGBITS signs.
__global__ __launch_bounds__(256) void attn(const float* __restrict__ q, const float* __restrict__ k,
                                            const float* __restrict__ kc, const float* __restrict__ v,
                                            float* __restrict__ y) {
    __shared__ float sq[4][64];
    int wave = threadIdx.x >> 6, lane = threadIdx.x & 63;
    int h = blockIdx.x >> 9;
    int i = (blockIdx.x & 511) * 4 + wave;
    int e = lane & 7, base = (lane >> 3) * 8;
    const float* qrow = q + (size_t)i * CDIM + h * HDIM;
    sq[wave][lane] = qrow[lane];
    __syncthreads();

    // s_e = sum_n SG[n^e][n] * q_{n^e} * kc_n ; out_e = sum_n SG[n^e][n] * s_{n^e} * v_n
    float qs2[8];
    u32 sgn[8];
    int lsrc[8];
#pragma unroll
    for (int n = 0; n < 8; ++n) {
        int a = n ^ e;
        float qa = qrow[base + a];
        u32 neg = (u32)((SGBITS >> (a * 8 + n)) & 1ULL);
        qs2[n] = neg ? -qa : qa;
        sgn[n] = neg << 31;
        lsrc[n] = base + a;
    }

    float acc = 0.f, run_m = -1e30f, run_l = 0.f;
    int ntile = (i >> 6) + 1;
    for (int tb = 0; tb < ntile; ++tb) {
        int j0 = tb << 6;
        int jj = j0 + lane;
        float sc = -1e30f;
        if (jj <= i) {
            const float* krow = k + (size_t)jj * CDIM + h * HDIM;
            float dot = 0.f;
#pragma unroll
            for (int d4 = 0; d4 < 16; ++d4) {
                float4 kv = ((const float4*)krow)[d4];
                float4 qv = ((const float4*)(&sq[wave][0]))[d4];
                dot = fmaf(kv.x, qv.x, fmaf(kv.y, qv.y, fmaf(kv.z, qv.z, fmaf(kv.w, qv.w, dot))));
            }
            sc = dot * 0.125f;  // HEAD_DIM^-0.5
        }
        float tm = sc;
#pragma unroll
        for (int m = 1; m < 64; m <<= 1) tm = fmaxf(tm, __shfl_xor(tm, m));
        float nm = fmaxf(run_m, tm);
        float al = __expf(run_m - nm);
        float pp = __expf(sc - nm);
        float ps = pp;
#pragma unroll
        for (int m = 1; m < 64; m <<= 1) ps += __shfl_xor(ps, m);
        run_l = fmaf(run_l, al, ps);
        run_m = nm;
        acc *= al;
        int jmax = min(63, i - j0);
        for (int t2 = 0; t2 <= jmax; ++t2) {
            float pj = __shfl(pp, t2);
            size_t jb = (size_t)(j0 + t2) * CDIM + h * HDIM + base;
            const float4* kcp = (const float4*)(kc + jb);
            const float4* vp = (const float4*)(v + jb);
            float4 c0 = kcp[0], c1 = kcp[1];
            float4 w0 = vp[0], w1 = vp[1];
            float kcv[8] = {c0.x, c0.y, c0.z, c0.w, c1.x, c1.y, c1.z, c1.w};
            float vv[8] = {w0.x, w0.y, w0.z, w0.w, w1.x, w1.y, w1.z, w1.w};
            float s = 0.f;
#pragma unroll
            for (int n = 0; n < 8; ++n) s = fmaf(qs2[n], kcv[n], s);
            float outv = 0.f;
#pragma unroll
            for (int n = 0; n < 8; ++n) {
                float sp = __shfl(s, lsrc[n]);
                sp = __uint_as_float(__float_as_uint(sp) ^ sgn[n]);
                outv = fmaf(sp, vv[n], outv);
            }
            acc = fmaf(pj, outv, acc);
        }
    }
    y[(size_t)i * CDIM + h * HDIM + lane] = acc / run_l;
}

extern "C" void kernel_launch(void* const* d_in, const int* in_sizes, int n_in,
                              void* d_out, int out_size, void* d_ws, size_t ws_size,
                              hipStream_t stream) {
    const float* x = (const float*)d_in[0];
    const float* cosb = (const float*)d_in[1];
    const float* sinb = (const float*)d_in[2];
    const float* Wq = (const float*)d_in[3];
    const float* Wk = (const float*)d_in[4];
    const float* Wv = (const float*)d_in[5];
    const float* Wo = (const float*)d_in[6];
    float* out = (float*)d_out;  // reference output dtype is float32
    float* ws = (float*)d_ws;
    const size_t NT = (size_t)T_SEQ * CDIM;
    float* q = ws;
    float* k = q + NT;
    float* v = k + NT;
    float* kc = v + NT;
    float* y = kc + NT;

    dim3 gg(CDIM / 64, T_SEQ / 128);
    gemm_ff_f<<<gg, 256, 0, stream>>>(x, Wq, q, T_SEQ, CDIM, CDIM);
    gemm_ff_f<<<gg, 256, 0, stream>>>(x, Wk, k, T_SEQ, CDIM, CDIM);
    gemm_ff_f<<<gg, 256, 0, stream>>>(x, Wv, v, T_SEQ, CDIM, CDIM);
    prep_rope<<<T_SEQ * NHEAD / 4, 256, 0, stream>>>(q, k, kc, cosb, sinb);
    attn<<<NHEAD * (T_SEQ / 4), 256, 0, stream>>>(q, k, kc, v, y);
    gemm_ff_f<<<gg, 256, 0, stream>>>(y, Wo, out, T_SEQ, CDIM, CDIM);
}

// Round 4
// 1234.489 us; speedup vs baseline: 4.4740x; 4.4740x over previous
//
#include <hip/hip_runtime.h>

typedef unsigned short u16;
typedef unsigned int u32;
typedef unsigned long long u64;

#define T_SEQ 2048
#define NHEAD 16
#define HDIM 64
#define CDIM 1024

// Octonion sign table: SG[a][n] = sign of component (a^n) of e_a * e_n.
// Byte a of SGBITS holds row a; bit n set => negative. (Validated end-to-end in round 3.)
#define SGBITS 0xB2D8741EACC66A00ULL

__device__ __forceinline__ float h2f(u16 u) { _Float16 h; __builtin_memcpy(&h, &u, 2); return (float)h; }
__device__ __forceinline__ u16 f2h(float f) { _Float16 h = (_Float16)f; u16 u; __builtin_memcpy(&u, &h, 2); return u; }

// C[i,n] = sum_c A[i,c] * B[n,c]  (A: MxK fp32, B: NxK fp32, C: MxN fp32)
__global__ __launch_bounds__(256) void gemm_ff_f(const float* __restrict__ A, const float* __restrict__ B,
                                                 float* __restrict__ C, int M, int N, int K) {
    __shared__ float As[16][132];
    __shared__ float Bs[16][68];
    int tid = threadIdx.x;
    int bm = blockIdx.y * 128, bn = blockIdx.x * 64;
    int alr = tid >> 1, alc = (tid & 1) * 8;
    int blr = tid >> 2, blc = (tid & 3) * 4;
    const float* Ap = A + (size_t)(bm + alr) * K + alc;
    const float* Bp = B + (size_t)(bn + blr) * K + blc;
    int tx = tid & 15, ty = tid >> 4;
    float acc[8][4];
#pragma unroll
    for (int i = 0; i < 8; ++i)
#pragma unroll
        for (int j = 0; j < 4; ++j) acc[i][j] = 0.f;
    for (int k0 = 0; k0 < K; k0 += 16) {
        float4 a0 = *(const float4*)(Ap + k0);
        float4 a1 = *(const float4*)(Ap + k0 + 4);
        float4 b0 = *(const float4*)(Bp + k0);
        __syncthreads();
        As[alc + 0][alr] = a0.x; As[alc + 1][alr] = a0.y;
        As[alc + 2][alr] = a0.z; As[alc + 3][alr] = a0.w;
        As[alc + 4][alr] = a1.x; As[alc + 5][alr] = a1.y;
        As[alc + 6][alr] = a1.z; As[alc + 7][alr] = a1.w;
        Bs[blc + 0][blr] = b0.x; Bs[blc + 1][blr] = b0.y;
        Bs[blc + 2][blr] = b0.z; Bs[blc + 3][blr] = b0.w;
        __syncthreads();
#pragma unroll
        for (int kk = 0; kk < 16; ++kk) {
            float av[8], bv[4];
#pragma unroll
            for (int u = 0; u < 8; ++u) av[u] = As[kk][ty * 8 + u];
#pragma unroll
            for (int u = 0; u < 4; ++u) bv[u] = Bs[kk][tx * 4 + u];
#pragma unroll
            for (int uy = 0; uy < 8; ++uy)
#pragma unroll
                for (int ux = 0; ux < 4; ++ux) acc[uy][ux] = fmaf(av[uy], bv[ux], acc[uy][ux]);
        }
    }
#pragma unroll
    for (int uy = 0; uy < 8; ++uy) {
        float4 o = make_float4(acc[uy][0], acc[uy][1], acc[uy][2], acc[uy][3]);
        *(float4*)(C + (size_t)(bm + ty * 8 + uy) * N + bn + tx * 4) = o;
    }
}

// One wave per (t, h): rotary -> RMS norm for q and k; octonion-normalized conjugated k -> kc.
__global__ __launch_bounds__(256) void prep_rope(float* __restrict__ q, float* __restrict__ k,
                                                 float* __restrict__ kc,
                                                 const float* __restrict__ cosb, const float* __restrict__ sinb) {
    int wave = threadIdx.x >> 6, lane = threadIdx.x & 63;
    int idx = blockIdx.x * 4 + wave;
    int t = idx >> 4, h = idx & 15;
    int d = lane & 31;
    float cs = cosb[t * 32 + d];
    float sn = sinb[t * 32 + d];
    size_t base = (size_t)t * CDIM + h * HDIM;

    float xq = q[base + lane];
    float oq = __shfl(xq, lane ^ 32);
    float rq = (lane < 32) ? fmaf(xq, cs, oq * sn) : fmaf(xq, cs, -oq * sn);
    float ssq = rq * rq;
#pragma unroll
    for (int m = 1; m < 64; m <<= 1) ssq += __shfl_xor(ssq, m);
    rq *= rsqrtf(ssq * (1.f / 64.f) + 1e-6f);
    q[base + lane] = rq;

    float xk = k[base + lane];
    float ok = __shfl(xk, lane ^ 32);
    float rk = (lane < 32) ? fmaf(xk, cs, ok * sn) : fmaf(xk, cs, -ok * sn);
    float ssk = rk * rk;
#pragma unroll
    for (int m = 1; m < 64; m <<= 1) ssk += __shfl_xor(ssk, m);
    rk *= rsqrtf(ssk * (1.f / 64.f) + 1e-6f);
    k[base + lane] = rk;

    float s8 = rk * rk;
    s8 += __shfl_xor(s8, 1); s8 += __shfl_xor(s8, 2); s8 += __shfl_xor(s8, 4);
    float sc2 = 1.f / fmaxf(sqrtf(s8), 1e-12f);
    float kcv = rk * sc2;
    if (lane & 7) kcv = -kcv;  // octonion conjugate: negate components 1..7
    kc[base + lane] = kcv;
}

// S[h][i][j] = 0.125 * sum_c q[i, h*64+c] * k[j, h*64+c]   (fp16 out, causal tiles only)
__global__ __launch_bounds__(256) void gemm_qk(const float* __restrict__ q, const float* __restrict__ k,
                                               u16* __restrict__ S) {
    int h = blockIdx.z;
    int bm = blockIdx.y * 128, bn = blockIdx.x * 64;
    if (bn > bm + 127) return;  // fully masked tile: softmax writes zeros there
    __shared__ float As[16][132];
    __shared__ float Bs[16][68];
    int tid = threadIdx.x;
    int alr = tid >> 1, alc = (tid & 1) * 8;
    int blr = tid >> 2, blc = (tid & 3) * 4;
    const float* Ap = q + (size_t)(bm + alr) * CDIM + h * HDIM + alc;
    const float* Bp = k + (size_t)(bn + blr) * CDIM + h * HDIM + blc;
    int tx = tid & 15, ty = tid >> 4;
    float acc[8][4];
#pragma unroll
    for (int i = 0; i < 8; ++i)
#pragma unroll
        for (int j = 0; j < 4; ++j) acc[i][j] = 0.f;
#pragma unroll
    for (int k0 = 0; k0 < 64; k0 += 16) {
        float4 a0 = *(const float4*)(Ap + k0);
        float4 a1 = *(const float4*)(Ap + k0 + 4);
        float4 b0 = *(const float4*)(Bp + k0);
        __syncthreads();
        As[alc + 0][alr] = a0.x; As[alc + 1][alr] = a0.y;
        As[alc + 2][alr] = a0.z; As[alc + 3][alr] = a0.w;
        As[alc + 4][alr] = a1.x; As[alc + 5][alr] = a1.y;
        As[alc + 6][alr] = a1.z; As[alc + 7][alr] = a1.w;
        Bs[blc + 0][blr] = b0.x; Bs[blc + 1][blr] = b0.y;
        Bs[blc + 2][blr] = b0.z; Bs[blc + 3][blr] = b0.w;
        __syncthreads();
#pragma unroll
        for (int kk = 0; kk < 16; ++kk) {
            float av[8], bv[4];
#pragma unroll
            for (int u = 0; u < 8; ++u) av[u] = As[kk][ty * 8 + u];
#pragma unroll
            for (int u = 0; u < 4; ++u) bv[u] = Bs[kk][tx * 4 + u];
#pragma unroll
            for (int uy = 0; uy < 8; ++uy)
#pragma unroll
                for (int ux = 0; ux < 4; ++ux) acc[uy][ux] = fmaf(av[uy], bv[ux], acc[uy][ux]);
        }
    }
    u16* Sp = S + (size_t)h * T_SEQ * T_SEQ;
#pragma unroll
    for (int uy = 0; uy < 8; ++uy) {
        ushort4 o;
        o.x = f2h(acc[uy][0] * 0.125f); o.y = f2h(acc[uy][1] * 0.125f);
        o.z = f2h(acc[uy][2] * 0.125f); o.w = f2h(acc[uy][3] * 0.125f);
        *(ushort4*)(Sp + (size_t)(bm + ty * 8 + uy) * T_SEQ + bn + tx * 4) = o;
    }
}

// In-place causal softmax over row (h,i); writes P (fp16), zeros for j > i.
__global__ __launch_bounds__(256) void softmax_rows(u16* __restrict__ S) {
    int wave = threadIdx.x >> 6, lane = threadIdx.x & 63;
    int idx = blockIdx.x * 4 + wave;
    int h = idx >> 11, i = idx & 2047;
    u16* row = S + (size_t)h * T_SEQ * T_SEQ + (size_t)i * T_SEQ;
    int n = i + 1;
    float m = -1e30f;
    for (int j = lane; j < n; j += 64) m = fmaxf(m, h2f(row[j]));
#pragma unroll
    for (int d = 1; d < 64; d <<= 1) m = fmaxf(m, __shfl_xor(m, d));
    float s = 0.f;
    for (int j = lane; j < n; j += 64) s += __expf(h2f(row[j]) - m);
#pragma unroll
    for (int d = 1; d < 64; d <<= 1) s += __shfl_xor(s, d);
    float inv = 1.f / s;
    for (int j = lane; j < T_SEQ; j += 64) {
        float p = (j < n) ? __expf(h2f(row[j]) - m) * inv : 0.f;
        row[j] = f2h(p);
    }
}

// W[h][n=(m*64+a*8+e)][j] = sum_t sg[a][a^e^t]*sg[e^t][t]*kc[j,h,m,a^e^t]*v[j,h,m,t]  (fp16)
__global__ __launch_bounds__(256) void w_pre(const float* __restrict__ kc, const float* __restrict__ v,
                                             u16* __restrict__ W) {
    __shared__ float kcs[64][65];
    __shared__ float vs[64][65];
    int h = blockIdx.y;
    int j0 = blockIdx.x * 64;
    int t = threadIdx.x;
    int r = t >> 2, cq = (t & 3) * 16;
    const float* kp = kc + (size_t)(j0 + r) * CDIM + h * HDIM + cq;
    const float* vp = v + (size_t)(j0 + r) * CDIM + h * HDIM + cq;
#pragma unroll
    for (int u4 = 0; u4 < 4; ++u4) {
        float4 a = *(const float4*)(kp + u4 * 4);
        float4 b = *(const float4*)(vp + u4 * 4);
        kcs[r][cq + u4 * 4 + 0] = a.x; kcs[r][cq + u4 * 4 + 1] = a.y;
        kcs[r][cq + u4 * 4 + 2] = a.z; kcs[r][cq + u4 * 4 + 3] = a.w;
        vs[r][cq + u4 * 4 + 0] = b.x; vs[r][cq + u4 * 4 + 1] = b.y;
        vs[r][cq + u4 * 4 + 2] = b.z; vs[r][cq + u4 * 4 + 3] = b.w;
    }
    __syncthreads();
    int j = t & 63, g = t >> 6;
    u16* Wp = W + (size_t)h * 512 * T_SEQ + j0 + j;
    for (int ae = g * 16; ae < g * 16 + 16; ++ae) {
        int a = ae >> 3, e = ae & 7;
        u32 mask = 0;
#pragma unroll
        for (int qq = 0; qq < 8; ++qq) {
            int p = a ^ e ^ qq;
            u32 bit = (u32)(((SGBITS >> (a * 8 + p)) ^ (SGBITS >> ((e ^ qq) * 8 + qq))) & 1ULL);
            mask |= bit << qq;
        }
#pragma unroll
        for (int m = 0; m < 8; ++m) {
            float w = 0.f;
#pragma unroll
            for (int qq = 0; qq < 8; ++qq) {
                float t1 = kcs[j][m * 8 + (a ^ e ^ qq)] * vs[j][m * 8 + qq];
                w = ((mask >> qq) & 1) ? (w - t1) : (w + t1);
            }
            Wp[(size_t)(m * 64 + ae) * T_SEQ] = f2h(w);
        }
    }
}

// Z[h][i][n] = sum_j P[h][i][j] * W[h][n][j]   (fp16 in/out, K limited to bm+128 by causality)
__global__ __launch_bounds__(256) void gemm_pw(const u16* __restrict__ P, const u16* __restrict__ W,
                                               u16* __restrict__ Z) {
    int h = blockIdx.z;
    int bm = blockIdx.y * 128, bn = blockIdx.x * 64;
    __shared__ float As[16][132];
    __shared__ float Bs[16][68];
    int tid = threadIdx.x;
    int alr = tid >> 1, alc = (tid & 1) * 8;
    int blr = tid >> 2, blc = (tid & 3) * 4;
    const u16* Ap = P + (size_t)h * T_SEQ * T_SEQ + (size_t)(bm + alr) * T_SEQ + alc;
    const u16* Bp = W + (size_t)h * 512 * T_SEQ + (size_t)(bn + blr) * T_SEQ + blc;
    int tx = tid & 15, ty = tid >> 4;
    float acc[8][4];
#pragma unroll
    for (int i = 0; i < 8; ++i)
#pragma unroll
        for (int j = 0; j < 4; ++j) acc[i][j] = 0.f;
    int kend = bm + 128;  // P[i][j]==0 for j>i, and i <= bm+127 in this tile
    for (int k0 = 0; k0 < kend; k0 += 16) {
        ushort4 a0 = *(const ushort4*)(Ap + k0);
        ushort4 a1 = *(const ushort4*)(Ap + k0 + 4);
        ushort4 b0 = *(const ushort4*)(Bp + k0);
        __syncthreads();
        As[alc + 0][alr] = h2f(a0.x); As[alc + 1][alr] = h2f(a0.y);
        As[alc + 2][alr] = h2f(a0.z); As[alc + 3][alr] = h2f(a0.w);
        As[alc + 4][alr] = h2f(a1.x); As[alc + 5][alr] = h2f(a1.y);
        As[alc + 6][alr] = h2f(a1.z); As[alc + 7][alr] = h2f(a1.w);
        Bs[blc + 0][blr] = h2f(b0.x); Bs[blc + 1][blr] = h2f(b0.y);
        Bs[blc + 2][blr] = h2f(b0.z); Bs[blc + 3][blr] = h2f(b0.w);
        __syncthreads();
#pragma unroll
        for (int kk = 0; kk < 16; ++kk) {
            float av[8], bv[4];
#pragma unroll
            for (int u = 0; u < 8; ++u) av[u] = As[kk][ty * 8 + u];
#pragma unroll
            for (int u = 0; u < 4; ++u) bv[u] = Bs[kk][tx * 4 + u];
#pragma unroll
            for (int uy = 0; uy < 8; ++uy)
#pragma unroll
                for (int ux = 0; ux < 4; ++ux) acc[uy][ux] = fmaf(av[uy], bv[ux], acc[uy][ux]);
        }
    }
    u16* Zp = Z + (size_t)h * T_SEQ * 512;
#pragma unroll
    for (int uy = 0; uy < 8; ++uy) {
        ushort4 o;
        o.x = f2h(acc[uy][0]); o.y = f2h(acc[uy][1]);
        o.z = f2h(acc[uy][2]); o.w = f2h(acc[uy][3]);
        *(ushort4*)(Zp + (size_t)(bm + ty * 8 + uy) * 512 + bn + tx * 4) = o;
    }
}

// y[i, h*64 + m*8 + e] = sum_a q[i, h*64 + m*8 + a] * Z[h][i][m*64 + a*8 + e]
__global__ __launch_bounds__(256) void contract_y(const float* __restrict__ q, const u16* __restrict__ Z,
                                                  float* __restrict__ y) {
    int wave = threadIdx.x >> 6, lane = threadIdx.x & 63;
    int idx = blockIdx.x * 4 + wave;
    int i = idx >> 4, h = idx & 15;
    int m = lane >> 3, e = lane & 7;
    const float* qp = q + (size_t)i * CDIM + h * HDIM + m * 8;
    float4 q0 = *(const float4*)(qp);
    float4 q1 = *(const float4*)(qp + 4);
    float qv[8] = {q0.x, q0.y, q0.z, q0.w, q1.x, q1.y, q1.z, q1.w};
    const u16* Zp = Z + (size_t)h * T_SEQ * 512 + (size_t)i * 512 + m * 64 + e;
    float acc = 0.f;
#pragma unroll
    for (int a = 0; a < 8; ++a) acc = fmaf(qv[a], h2f(Zp[a * 8]), acc);
    y[(size_t)i * CDIM + h * HDIM + lane] = acc;
}

// ---------------- fallback (round-3, known passing) ----------------
__global__ __launch_bounds__(256) void attn(const float* __restrict__ q, const float* __restrict__ k,
                                            const float* __restrict__ kc, const float* __restrict__ v,
                                            float* __restrict__ y) {
    __shared__ float sq[4][64];
    int wave = threadIdx.x >> 6, lane = threadIdx.x & 63;
    int h = blockIdx.x >> 9;
    int i = (blockIdx.x & 511) * 4 + wave;
    int e = lane & 7, base = (lane >> 3) * 8;
    const float* qrow = q + (size_t)i * CDIM + h * HDIM;
    sq[wave][lane] = qrow[lane];
    __syncthreads();
    float qs2[8];
    u32 sgn[8];
    int lsrc[8];
#pragma unroll
    for (int n = 0; n < 8; ++n) {
        int a = n ^ e;
        float qa = qrow[base + a];
        u32 neg = (u32)((SGBITS >> (a * 8 + n)) & 1ULL);
        qs2[n] = neg ? -qa : qa;
        sgn[n] = neg << 31;
        lsrc[n] = base + a;
    }
    float acc = 0.f, run_m = -1e30f, run_l = 0.f;
    int ntile = (i >> 6) + 1;
    for (int tb = 0; tb < ntile; ++tb) {
        int j0 = tb << 6;
        int jj = j0 + lane;
        float sc = -1e30f;
        if (jj <= i) {
            const float* krow = k + (size_t)jj * CDIM + h * HDIM;
            float dot = 0.f;
#pragma unroll
            for (int d4 = 0; d4 < 16; ++d4) {
                float4 kv = ((const float4*)krow)[d4];
                float4 qv = ((const float4*)(&sq[wave][0]))[d4];
                dot = fmaf(kv.x, qv.x, fmaf(kv.y, qv.y, fmaf(kv.z, qv.z, fmaf(kv.w, qv.w, dot))));
            }
            sc = dot * 0.125f;
        }
        float tm = sc;
#pragma unroll
        for (int m = 1; m < 64; m <<= 1) tm = fmaxf(tm, __shfl_xor(tm, m));
        float nm = fmaxf(run_m, tm);
        float al = __expf(run_m - nm);
        float pp = __expf(sc - nm);
        float ps = pp;
#pragma unroll
        for (int m = 1; m < 64; m <<= 1) ps += __shfl_xor(ps, m);
        run_l = fmaf(run_l, al, ps);
        run_m = nm;
        acc *= al;
        int jmax = min(63, i - j0);
        for (int t2 = 0; t2 <= jmax; ++t2) {
            float pj = __shfl(pp, t2);
            size_t jb = (size_t)(j0 + t2) * CDIM + h * HDIM + base;
            const float4* kcp = (const float4*)(kc + jb);
            const float4* vp = (const float4*)(v + jb);
            float4 c0 = kcp[0], c1 = kcp[1];
            float4 w0 = vp[0], w1 = vp[1];
            float kcv[8] = {c0.x, c0.y, c0.z, c0.w, c1.x, c1.y, c1.z, c1.w};
            float vv[8] = {w0.x, w0.y, w0.z, w0.w, w1.x, w1.y, w1.z, w1.w};
            float s = 0.f;
#pragma unroll
            for (int n = 0; n < 8; ++n) s = fmaf(qs2[n], kcv[n], s);
            float outv = 0.f;
#pragma unroll
            for (int n = 0; n < 8; ++n) {
                float sp = __shfl(s, lsrc[n]);
                sp = __uint_as_float(__float_as_uint(sp) ^ sgn[n]);
                outv = fmaf(sp, vv[n], outv);
            }
            acc = fmaf(pj, outv, acc);
        }
    }
    y[(size_t)i * CDIM + h * HDIM + lane] = acc / run_l;
}

extern "C" void kernel_launch(void* const* d_in, const int* in_sizes, int n_in,
                              void* d_out, int out_size, void* d_ws, size_t ws_size,
                              hipStream_t stream) {
    const float* x = (const float*)d_in[0];
    const float* cosb = (const float*)d_in[1];
    const float* sinb = (const float*)d_in[2];
    const float* Wq = (const float*)d_in[3];
    const float* Wk = (const float*)d_in[4];
    const float* Wv = (const float*)d_in[5];
    const float* Wo = (const float*)d_in[6];
    float* out = (float*)d_out;
    float* ws = (float*)d_ws;
    const size_t NT = (size_t)T_SEQ * CDIM;
    float* q = ws;
    float* k = q + NT;
    float* v = k + NT;
    float* kc = v + NT;
    float* y = kc + NT;
    u16* S = (u16*)(y + NT);                       // 16*2048*2048 fp16 = 134.2 MB
    u16* W = S + (size_t)NHEAD * T_SEQ * T_SEQ;    // 16*512*2048  fp16 = 33.6 MB
    u16* Z = W + (size_t)NHEAD * 512 * T_SEQ;      // 16*2048*512  fp16 = 33.6 MB
    const size_t NEED = 5 * NT * 4 + (size_t)NHEAD * T_SEQ * T_SEQ * 2 + 2 * (size_t)NHEAD * 512 * T_SEQ * 2;

    dim3 gg(CDIM / 64, T_SEQ / 128);
    gemm_ff_f<<<gg, 256, 0, stream>>>(x, Wq, q, T_SEQ, CDIM, CDIM);
    gemm_ff_f<<<gg, 256, 0, stream>>>(x, Wk, k, T_SEQ, CDIM, CDIM);
    gemm_ff_f<<<gg, 256, 0, stream>>>(x, Wv, v, T_SEQ, CDIM, CDIM);
    prep_rope<<<T_SEQ * NHEAD / 4, 256, 0, stream>>>(q, k, kc, cosb, sinb);

    if (ws_size >= NEED) {
        gemm_qk<<<dim3(32, 16, 16), 256, 0, stream>>>(q, k, S);
        softmax_rows<<<NHEAD * T_SEQ / 4, 256, 0, stream>>>(S);
        w_pre<<<dim3(32, 16), 256, 0, stream>>>(kc, v, W);
        gemm_pw<<<dim3(8, 16, 16), 256, 0, stream>>>(S, W, Z);
        contract_y<<<NHEAD * T_SEQ / 4, 256, 0, stream>>>(q, Z, y);
    } else {
        attn<<<NHEAD * (T_SEQ / 4), 256, 0, stream>>>(q, k, kc, v, y);
    }
    gemm_ff_f<<<gg, 256, 0, stream>>>(y, Wo, out, T_SEQ, CDIM, CDIM);
}

// Round 5
// 363.383 us; speedup vs baseline: 15.1993x; 3.3972x over previous
//
#include <hip/hip_runtime.h>

typedef unsigned short u16;
typedef unsigned int u32;

#define T_SEQ 2048
#define NHEAD 16
#define HDIM 64
#define CDIM 1024
#define S_HSTR 2228224   // per-head packed-S elements: 136 tiles * 16384
#define W_HSTR (512*2048)
#define Z_HSTR (2048*512)

// Octonion sign table: SG[a][n] = sign of component (a^n) of e_a * e_n.
// Byte a holds row a; bit n set => negative. (Validated end-to-end rounds 3-4.)
#define SGBITS 0xB2D8741EACC66A00ULL

typedef _Float16 f16x8 __attribute__((ext_vector_type(8)));
typedef float f32x4 __attribute__((ext_vector_type(4)));

__device__ __forceinline__ float h2f(u16 u) { _Float16 h; __builtin_memcpy(&h, &u, 2); return (float)h; }
__device__ __forceinline__ u16 f2h(float f) { _Float16 h = (_Float16)f; u16 u; __builtin_memcpy(&u, &h, 2); return u; }
__device__ __forceinline__ u32 pk(float a, float b) { return (u32)f2h(a) | ((u32)f2h(b) << 16); }

// ---- shared MFMA tile: C(128x128) = A(128xK) * B(128xK)^T, fp16 in, fp32 acc ----
// At/Bt point at the tile's row-0; LDS rows padded 32->40 halves to break bank conflicts.
template<bool F16OUT>
__device__ __forceinline__ void hgemm_tile(const u16* __restrict__ At, int lda,
                                           const u16* __restrict__ Bt, int ldb, int K,
                                           float* __restrict__ Cf, u16* __restrict__ Ch,
                                           int ldc, float scale, u16* As, u16* Bs) {
    int t = threadIdx.x;
    int wave = t >> 6, l = t & 63;
    int wm = wave & 1, wn = wave >> 1;
    int quad = l >> 4, lr = l & 15;
    int r0 = t >> 2, c0 = (t & 3) * 8;
    f32x4 acc[4][4];
#pragma unroll
    for (int i = 0; i < 4; ++i)
#pragma unroll
        for (int j = 0; j < 4; ++j) acc[i][j] = (f32x4){0.f, 0.f, 0.f, 0.f};
    for (int k0 = 0; k0 < K; k0 += 32) {
        uint4 a0 = *(const uint4*)(At + (size_t)r0 * lda + k0 + c0);
        uint4 a1 = *(const uint4*)(At + (size_t)(r0 + 64) * lda + k0 + c0);
        uint4 b0 = *(const uint4*)(Bt + (size_t)r0 * ldb + k0 + c0);
        uint4 b1 = *(const uint4*)(Bt + (size_t)(r0 + 64) * ldb + k0 + c0);
        __syncthreads();
        *(uint4*)&As[r0 * 40 + c0] = a0;
        *(uint4*)&As[(r0 + 64) * 40 + c0] = a1;
        *(uint4*)&Bs[r0 * 40 + c0] = b0;
        *(uint4*)&Bs[(r0 + 64) * 40 + c0] = b1;
        __syncthreads();
        f16x8 af[4], bf[4];
#pragma unroll
        for (int mi = 0; mi < 4; ++mi) af[mi] = *(const f16x8*)&As[(wm * 64 + mi * 16 + lr) * 40 + quad * 8];
#pragma unroll
        for (int ni = 0; ni < 4; ++ni) bf[ni] = *(const f16x8*)&Bs[(wn * 64 + ni * 16 + lr) * 40 + quad * 8];
#pragma unroll
        for (int mi = 0; mi < 4; ++mi)
#pragma unroll
            for (int ni = 0; ni < 4; ++ni)
                acc[mi][ni] = __builtin_amdgcn_mfma_f32_16x16x32_f16(af[mi], bf[ni], acc[mi][ni], 0, 0, 0);
    }
#pragma unroll
    for (int mi = 0; mi < 4; ++mi)
#pragma unroll
        for (int ni = 0; ni < 4; ++ni)
#pragma unroll
            for (int rr = 0; rr < 4; ++rr) {
                int gr = wm * 64 + mi * 16 + quad * 4 + rr;
                int gc = wn * 64 + ni * 16 + lr;
                float v = acc[mi][ni][rr] * scale;
                if (F16OUT) Ch[(size_t)gr * ldc + gc] = f2h(v);
                else Cf[(size_t)gr * ldc + gc] = v;
            }
}

// generic C[i,n] = sum_c A[i,c]*B[n,c], fp32 out
__global__ __launch_bounds__(256) void hgemm_f32(const u16* __restrict__ A, int lda,
                                                 const u16* __restrict__ B, int ldb,
                                                 float* __restrict__ C, int ldc, int K) {
    __shared__ u16 As[128 * 40], Bs[128 * 40];
    int bm = blockIdx.y * 128, bn = blockIdx.x * 128;
    hgemm_tile<false>(A + (size_t)bm * lda, lda, B + (size_t)bn * ldb, ldb, K,
                      C + (size_t)bm * ldc + bn, nullptr, ldc, 1.f, As, Bs);
}

// S packed-causal: tile (rb,cb<=rb) of scores*0.125, fp16
__global__ __launch_bounds__(256) void hgemm_qk(const u16* __restrict__ q16, const u16* __restrict__ k16,
                                                u16* __restrict__ S) {
    int h = blockIdx.z, rb = blockIdx.y, cb = blockIdx.x;
    if (cb > rb) return;
    __shared__ u16 As[128 * 40], Bs[128 * 40];
    int ld = (rb + 1) * 128;
    u16* Sb = S + (size_t)h * S_HSTR + (size_t)(rb * (rb + 1) / 2) * 16384 + cb * 128;
    hgemm_tile<true>(q16 + (size_t)rb * 128 * CDIM + h * HDIM, CDIM,
                     k16 + (size_t)cb * 128 * CDIM + h * HDIM, CDIM, HDIM,
                     nullptr, Sb, ld, 0.125f, As, Bs);
}

// Z[h][i][n] = sum_j P[i,j]*W[n,j]; packed A, K = (rb+1)*128 by causality
__global__ __launch_bounds__(256) void hgemm_pw(const u16* __restrict__ S, const u16* __restrict__ W,
                                                u16* __restrict__ Z) {
    int h = blockIdx.z, rb = blockIdx.y, bn = blockIdx.x * 128;
    __shared__ u16 As[128 * 40], Bs[128 * 40];
    int kend = (rb + 1) * 128;
    const u16* Ab = S + (size_t)h * S_HSTR + (size_t)(rb * (rb + 1) / 2) * 16384;
    const u16* Bb = W + (size_t)h * W_HSTR + (size_t)bn * T_SEQ;
    u16* Zb = Z + (size_t)h * Z_HSTR + (size_t)rb * 128 * 512 + bn;
    hgemm_tile<true>(Ab, kend, Bb, T_SEQ, kend, nullptr, Zb, 512, 1.f, As, Bs);
}

// fp32 -> fp16 conversions: z=0 x(2M), z=1..4 Wq/Wk/Wv/Wo (1M each) into w16
__global__ __launch_bounds__(256) void cvt5(const float* __restrict__ x, const float* __restrict__ wq,
                                            const float* __restrict__ wk, const float* __restrict__ wv,
                                            const float* __restrict__ wo,
                                            u16* __restrict__ x16, u16* __restrict__ w16) {
    int z = blockIdx.y;
    size_t base = ((size_t)blockIdx.x * 256 + threadIdx.x) * 8;
    const float* src;
    u16* dst;
    size_t cnt;
    if (z == 0) { src = x; dst = x16; cnt = 2097152; }
    else if (z == 1) { src = wq; dst = w16; cnt = 1048576; }
    else if (z == 2) { src = wk; dst = w16 + 1048576; cnt = 1048576; }
    else if (z == 3) { src = wv; dst = w16 + 2097152; cnt = 1048576; }
    else { src = wo; dst = w16 + 3145728; cnt = 1048576; }
    if (base >= cnt) return;
    float4 f0 = *(const float4*)(src + base);
    float4 f1 = *(const float4*)(src + base + 4);
    uint4 o;
    o.x = pk(f0.x, f0.y); o.y = pk(f0.z, f0.w); o.z = pk(f1.x, f1.y); o.w = pk(f1.z, f1.w);
    *(uint4*)(dst + base) = o;
}

// One wave per (t,h): rotary+RMS for q,k from fused qkv (ld 3072); writes q16,k16 (fp16), kc (fp32).
__global__ __launch_bounds__(256) void prep_rope(const float* __restrict__ qkv,
                                                 u16* __restrict__ q16, u16* __restrict__ k16,
                                                 float* __restrict__ kc,
                                                 const float* __restrict__ cosb, const float* __restrict__ sinb) {
    int wave = threadIdx.x >> 6, lane = threadIdx.x & 63;
    int idx = blockIdx.x * 4 + wave;
    int t = idx >> 4, h = idx & 15;
    int d = lane & 31;
    float cs = cosb[t * 32 + d];
    float sn = sinb[t * 32 + d];
    size_t b3 = (size_t)t * 3072 + h * HDIM;
    size_t b1 = (size_t)t * CDIM + h * HDIM;

    float xq = qkv[b3 + lane];
    float oq = __shfl(xq, lane ^ 32);
    float rq = (lane < 32) ? fmaf(xq, cs, oq * sn) : fmaf(xq, cs, -oq * sn);
    float ssq = rq * rq;
#pragma unroll
    for (int m = 1; m < 64; m <<= 1) ssq += __shfl_xor(ssq, m);
    rq *= rsqrtf(ssq * (1.f / 64.f) + 1e-6f);
    q16[b1 + lane] = f2h(rq);

    float xk = qkv[b3 + 1024 + lane];
    float ok = __shfl(xk, lane ^ 32);
    float rk = (lane < 32) ? fmaf(xk, cs, ok * sn) : fmaf(xk, cs, -ok * sn);
    float ssk = rk * rk;
#pragma unroll
    for (int m = 1; m < 64; m <<= 1) ssk += __shfl_xor(ssk, m);
    rk *= rsqrtf(ssk * (1.f / 64.f) + 1e-6f);
    k16[b1 + lane] = f2h(rk);

    float s8 = rk * rk;
    s8 += __shfl_xor(s8, 1); s8 += __shfl_xor(s8, 2); s8 += __shfl_xor(s8, 4);
    float sc2 = 1.f / fmaxf(sqrtf(s8), 1e-12f);
    float kcv = rk * sc2;
    if (lane & 7) kcv = -kcv;  // octonion conjugate
    kc[b1 + lane] = kcv;
}

// Causal softmax over packed row (h,i): valid j<=i, zero-fill to ld.
__global__ __launch_bounds__(256) void softmax_rows(u16* __restrict__ S) {
    int wave = threadIdx.x >> 6, lane = threadIdx.x & 63;
    int idx = blockIdx.x * 4 + wave;
    int h = idx >> 11, i = idx & 2047;
    int rb = i >> 7, ld = (rb + 1) * 128;
    u16* row = S + (size_t)h * S_HSTR + (size_t)(rb * (rb + 1) / 2) * 16384 + (size_t)(i & 127) * ld;
    int n = i + 1;
    float m = -1e30f;
    for (int j = lane; j < n; j += 64) m = fmaxf(m, h2f(row[j]));
#pragma unroll
    for (int d = 1; d < 64; d <<= 1) m = fmaxf(m, __shfl_xor(m, d));
    float s = 0.f;
    for (int j = lane; j < n; j += 64) s += __expf(h2f(row[j]) - m);
#pragma unroll
    for (int d = 1; d < 64; d <<= 1) s += __shfl_xor(s, d);
    float inv = 1.f / s;
    for (int j = lane; j < ld; j += 64) {
        float p = (j < n) ? __expf(h2f(row[j]) - m) * inv : 0.f;
        row[j] = f2h(p);
    }
}

// W[h][n=(m*64+a*8+e)][j] from kc (fp32, ld 1024) and v inside qkv (fp32, ld 3072, +2048)
__global__ __launch_bounds__(256) void w_pre(const float* __restrict__ kc, const float* __restrict__ qkv,
                                             u16* __restrict__ W) {
    __shared__ float kcs[64][65];
    __shared__ float vs[64][65];
    int h = blockIdx.y;
    int j0 = blockIdx.x * 64;
    int t = threadIdx.x;
    int r = t >> 2, cq = (t & 3) * 16;
    const float* kp = kc + (size_t)(j0 + r) * CDIM + h * HDIM + cq;
    const float* vp = qkv + (size_t)(j0 + r) * 3072 + 2048 + h * HDIM + cq;
#pragma unroll
    for (int u4 = 0; u4 < 4; ++u4) {
        float4 a = *(const float4*)(kp + u4 * 4);
        float4 b = *(const float4*)(vp + u4 * 4);
        kcs[r][cq + u4 * 4 + 0] = a.x; kcs[r][cq + u4 * 4 + 1] = a.y;
        kcs[r][cq + u4 * 4 + 2] = a.z; kcs[r][cq + u4 * 4 + 3] = a.w;
        vs[r][cq + u4 * 4 + 0] = b.x; vs[r][cq + u4 * 4 + 1] = b.y;
        vs[r][cq + u4 * 4 + 2] = b.z; vs[r][cq + u4 * 4 + 3] = b.w;
    }
    __syncthreads();
    int j = t & 63, g = t >> 6;
    u16* Wp = W + (size_t)h * W_HSTR + j0 + j;
    for (int ae = g * 16; ae < g * 16 + 16; ++ae) {
        int a = ae >> 3, e = ae & 7;
        u32 mask = 0;
#pragma unroll
        for (int qq = 0; qq < 8; ++qq) {
            int p = a ^ e ^ qq;
            u32 bit = (u32)(((SGBITS >> (a * 8 + p)) ^ (SGBITS >> ((e ^ qq) * 8 + qq))) & 1ULL);
            mask |= bit << qq;
        }
#pragma unroll
        for (int m = 0; m < 8; ++m) {
            float w = 0.f;
#pragma unroll
            for (int qq = 0; qq < 8; ++qq) {
                float t1 = kcs[j][m * 8 + (a ^ e ^ qq)] * vs[j][m * 8 + qq];
                w = ((mask >> qq) & 1) ? (w - t1) : (w + t1);
            }
            Wp[(size_t)(m * 64 + ae) * T_SEQ] = f2h(w);
        }
    }
}

// y16[i, h*64+m*8+e] = sum_a q16[i, h*64+m*8+a] * Z[h][i][m*64+a*8+e]
__global__ __launch_bounds__(256) void contract_y(const u16* __restrict__ q16, const u16* __restrict__ Z,
                                                  u16* __restrict__ y16) {
    int wave = threadIdx.x >> 6, lane = threadIdx.x & 63;
    int idx = blockIdx.x * 4 + wave;
    int i = idx >> 4, h = idx & 15;
    int m = lane >> 3, e = lane & 7;
    const u16* qp = q16 + (size_t)i * CDIM + h * HDIM + m * 8;
    uint4 qb = *(const uint4*)qp;
    float qv[8];
    qv[0] = h2f(qb.x & 0xffff); qv[1] = h2f(qb.x >> 16);
    qv[2] = h2f(qb.y & 0xffff); qv[3] = h2f(qb.y >> 16);
    qv[4] = h2f(qb.z & 0xffff); qv[5] = h2f(qb.z >> 16);
    qv[6] = h2f(qb.w & 0xffff); qv[7] = h2f(qb.w >> 16);
    const u16* Zp = Z + (size_t)h * Z_HSTR + (size_t)i * 512 + m * 64 + e;
    float acc = 0.f;
#pragma unroll
    for (int a = 0; a < 8; ++a) acc = fmaf(qv[a], h2f(Zp[a * 8]), acc);
    y16[(size_t)i * CDIM + h * HDIM + lane] = f2h(acc);
}

extern "C" void kernel_launch(void* const* d_in, const int* in_sizes, int n_in,
                              void* d_out, int out_size, void* d_ws, size_t ws_size,
                              hipStream_t stream) {
    const float* x = (const float*)d_in[0];
    const float* cosb = (const float*)d_in[1];
    const float* sinb = (const float*)d_in[2];
    const float* Wq = (const float*)d_in[3];
    const float* Wk = (const float*)d_in[4];
    const float* Wv = (const float*)d_in[5];
    const float* Wo = (const float*)d_in[6];
    float* out = (float*)d_out;
    char* base = (char*)d_ws;
    // workspace layout (197.1 MB total; round-4 evidence: ws >= 243.3 MB)
    float* qkv = (float*)base;                    // 2048x3072 fp32   25,165,824 B
    float* kc = (float*)(base + 25165824);        // 2048x1024 fp32    8,388,608
    u16* x16 = (u16*)(base + 33554432);           // 2048x1024 fp16    4,194,304
    u16* w16 = (u16*)(base + 37748736);           // 4x 1024x1024 fp16 8,388,608
    u16* q16 = (u16*)(base + 46137344);           //                   4,194,304
    u16* k16 = (u16*)(base + 50331648);           //                   4,194,304
    u16* y16 = (u16*)(base + 54525952);           //                   4,194,304
    u16* S = (u16*)(base + 58720256);             // packed causal    71,303,168
    u16* W = (u16*)(base + 130023424);            //                  33,554,432
    u16* Z = (u16*)(base + 163577856);            //                  33,554,432

    cvt5<<<dim3(1024, 5), 256, 0, stream>>>(x, Wq, Wk, Wv, Wo, x16, w16);
    // fused QKV projection: qkv[i, 0:3072] = x @ [Wq|Wk|Wv]^T
    hgemm_f32<<<dim3(24, 16), 256, 0, stream>>>(x16, CDIM, w16, CDIM, qkv, 3072, CDIM);
    prep_rope<<<T_SEQ * NHEAD / 4, 256, 0, stream>>>(qkv, q16, k16, kc, cosb, sinb);
    hgemm_qk<<<dim3(16, 16, 16), 256, 0, stream>>>(q16, k16, S);
    softmax_rows<<<NHEAD * T_SEQ / 4, 256, 0, stream>>>(S);
    w_pre<<<dim3(32, 16), 256, 0, stream>>>(kc, qkv, W);
    hgemm_pw<<<dim3(4, 16, 16), 256, 0, stream>>>(S, W, Z);
    contract_y<<<NHEAD * T_SEQ / 4, 256, 0, stream>>>(q16, Z, y16);
    // out = y @ Wo^T
    hgemm_f32<<<dim3(8, 16), 256, 0, stream>>>(y16, CDIM, w16 + 3145728, CDIM, out, CDIM, CDIM);
}

// Round 6
// 358.367 us; speedup vs baseline: 15.4120x; 1.0140x over previous
//
#include <hip/hip_runtime.h>

typedef unsigned short u16;
typedef unsigned int u32;

#define T_SEQ 2048
#define NHEAD 16
#define HDIM 64
#define CDIM 1024
#define S_HSTR 2228224   // per-head packed-S elements: 136 tiles * 16384
#define W_HSTR (512*2048)
#define Z_HSTR (2048*512)

// Octonion sign table: SG[a][n] = sign of component (a^n) of e_a * e_n.
// Byte a holds row a; bit n set => negative. (Validated end-to-end rounds 3-5.)
#define SGBITS 0xB2D8741EACC66A00ULL

typedef _Float16 f16x8 __attribute__((ext_vector_type(8)));
typedef float f32x4 __attribute__((ext_vector_type(4)));

__device__ __forceinline__ float h2f(u16 u) { _Float16 h; __builtin_memcpy(&h, &u, 2); return (float)h; }
__device__ __forceinline__ u16 f2h(float f) { _Float16 h = (_Float16)f; u16 u; __builtin_memcpy(&u, &h, 2); return u; }
__device__ __forceinline__ u32 pk(float a, float b) { return (u32)f2h(a) | ((u32)f2h(b) << 16); }

// async 16B/lane global->LDS DMA; lds dest must be wave-uniform (HW adds lane*16)
__device__ __forceinline__ void gload16(const u16* g, u16* l) {
    __builtin_amdgcn_global_load_lds((const __attribute__((address_space(1))) u32*)g,
                                     (__attribute__((address_space(3))) u32*)l, 16, 0, 0);
}

// ---- shared MFMA tile: C(128x128) = A(128xK) * B(128xK)^T, fp16 in, fp32 acc ----
// Fragment-major LDS: chunk d (1KB) = {kb=d>>3, seg=d&7}; slot lane*16B holds
// row 16*seg+(lane&15), halves kb*32+(lane>>4)*8 .. +7.  A-frag (16x16x32 f16,
// A[m=lane&15][k=quad*8+j]) = one ds_read_b128 at chunk_base + lane*16 -- conflict-free.
template<bool F16OUT>
__device__ __forceinline__ void hgemm_tile(const u16* __restrict__ At, int lda,
                                           const u16* __restrict__ Bt, int ldb, int K,
                                           float* __restrict__ Cf, u16* __restrict__ Ch,
                                           int ldc, float scale, u16* As, u16* Bs) {
    int t = threadIdx.x;
    int wave = t >> 6, l = t & 63;
    int wm = wave & 1, wn = wave >> 1;
    int quad = l >> 4, lr = l & 15;
    f32x4 acc[4][4];
#pragma unroll
    for (int i = 0; i < 4; ++i)
#pragma unroll
        for (int j = 0; j < 4; ++j) acc[i][j] = (f32x4){0.f, 0.f, 0.f, 0.f};
    int acol = quad * 8;  // halves within a 32-k block
    for (int k0 = 0; k0 < K; k0 += 64) {
#pragma unroll
        for (int j = 0; j < 4; ++j) {
            int d = wave * 4 + j;           // chunk 0..15
            int kb = d >> 3, seg = d & 7;
            size_t roff = (size_t)(seg * 16 + lr);
            int coff = k0 + kb * 32 + acol;
            gload16(At + roff * lda + coff, As + d * 512);
            gload16(Bt + roff * ldb + coff, Bs + d * 512);
        }
        __syncthreads();   // vmcnt(0) drain inserted by compiler
#pragma unroll
        for (int kb = 0; kb < 2; ++kb) {
            f16x8 af[4], bf[4];
#pragma unroll
            for (int mi = 0; mi < 4; ++mi) af[mi] = *(const f16x8*)&As[(kb * 8 + wm * 4 + mi) * 512 + l * 8];
#pragma unroll
            for (int ni = 0; ni < 4; ++ni) bf[ni] = *(const f16x8*)&Bs[(kb * 8 + wn * 4 + ni) * 512 + l * 8];
#pragma unroll
            for (int mi = 0; mi < 4; ++mi)
#pragma unroll
                for (int ni = 0; ni < 4; ++ni)
                    acc[mi][ni] = __builtin_amdgcn_mfma_f32_16x16x32_f16(af[mi], bf[ni], acc[mi][ni], 0, 0, 0);
        }
        __syncthreads();
    }
#pragma unroll
    for (int mi = 0; mi < 4; ++mi)
#pragma unroll
        for (int ni = 0; ni < 4; ++ni)
#pragma unroll
            for (int rr = 0; rr < 4; ++rr) {
                int gr = wm * 64 + mi * 16 + quad * 4 + rr;
                int gc = wn * 64 + ni * 16 + lr;
                float v = acc[mi][ni][rr] * scale;
                if (F16OUT) Ch[(size_t)gr * ldc + gc] = f2h(v);
                else Cf[(size_t)gr * ldc + gc] = v;
            }
}

// generic C[i,n] = sum_c A[i,c]*B[n,c], fp32 out
__global__ __launch_bounds__(256) void hgemm_f32(const u16* __restrict__ A, int lda,
                                                 const u16* __restrict__ B, int ldb,
                                                 float* __restrict__ C, int ldc, int K) {
    __shared__ u16 As[8192], Bs[8192];
    int bm = blockIdx.y * 128, bn = blockIdx.x * 128;
    hgemm_tile<false>(A + (size_t)bm * lda, lda, B + (size_t)bn * ldb, ldb, K,
                      C + (size_t)bm * ldc + bn, nullptr, ldc, 1.f, As, Bs);
}

// S packed-causal: tile (rb,cb<=rb) of scores*0.125, fp16
__global__ __launch_bounds__(256) void hgemm_qk(const u16* __restrict__ q16, const u16* __restrict__ k16,
                                                u16* __restrict__ S) {
    int h = blockIdx.z, rb = blockIdx.y, cb = blockIdx.x;
    if (cb > rb) return;
    __shared__ u16 As[8192], Bs[8192];
    int ld = (rb + 1) * 128;
    u16* Sb = S + (size_t)h * S_HSTR + (size_t)(rb * (rb + 1) / 2) * 16384 + cb * 128;
    hgemm_tile<true>(q16 + (size_t)rb * 128 * CDIM + h * HDIM, CDIM,
                     k16 + (size_t)cb * 128 * CDIM + h * HDIM, CDIM, HDIM,
                     nullptr, Sb, ld, 0.125f, As, Bs);
}

// Z[h][i][n] = sum_j P[i,j]*W[n,j]; packed A, K = (rb+1)*128 by causality.
// 1D grid, LPT order: heaviest rb dispatched first to kill the tail.
__global__ __launch_bounds__(256) void hgemm_pw(const u16* __restrict__ S, const u16* __restrict__ W,
                                                u16* __restrict__ Z) {
    int idx = blockIdx.x;              // 0..1023
    int rb = 15 - (idx >> 6);
    int sub = idx & 63;
    int h = sub >> 2, bn = (sub & 3) * 128;
    __shared__ u16 As[8192], Bs[8192];
    int kend = (rb + 1) * 128;
    const u16* Ab = S + (size_t)h * S_HSTR + (size_t)(rb * (rb + 1) / 2) * 16384;
    const u16* Bb = W + (size_t)h * W_HSTR + (size_t)bn * T_SEQ;
    u16* Zb = Z + (size_t)h * Z_HSTR + (size_t)rb * 128 * 512 + bn;
    hgemm_tile<true>(Ab, kend, Bb, T_SEQ, kend, nullptr, Zb, 512, 1.f, As, Bs);
}

// fp32 -> fp16 conversions: z=0 x(2M), z=1..4 Wq/Wk/Wv/Wo (1M each) into w16
__global__ __launch_bounds__(256) void cvt5(const float* __restrict__ x, const float* __restrict__ wq,
                                            const float* __restrict__ wk, const float* __restrict__ wv,
                                            const float* __restrict__ wo,
                                            u16* __restrict__ x16, u16* __restrict__ w16) {
    int z = blockIdx.y;
    size_t base = ((size_t)blockIdx.x * 256 + threadIdx.x) * 8;
    const float* src;
    u16* dst;
    size_t cnt;
    if (z == 0) { src = x; dst = x16; cnt = 2097152; }
    else if (z == 1) { src = wq; dst = w16; cnt = 1048576; }
    else if (z == 2) { src = wk; dst = w16 + 1048576; cnt = 1048576; }
    else if (z == 3) { src = wv; dst = w16 + 2097152; cnt = 1048576; }
    else { src = wo; dst = w16 + 3145728; cnt = 1048576; }
    if (base >= cnt) return;
    float4 f0 = *(const float4*)(src + base);
    float4 f1 = *(const float4*)(src + base + 4);
    uint4 o;
    o.x = pk(f0.x, f0.y); o.y = pk(f0.z, f0.w); o.z = pk(f1.x, f1.y); o.w = pk(f1.z, f1.w);
    *(uint4*)(dst + base) = o;
}

// One wave per (t,h): rotary+RMS for q,k from fused qkv (ld 3072); writes q16,k16 (fp16), kc (fp32).
__global__ __launch_bounds__(256) void prep_rope(const float* __restrict__ qkv,
                                                 u16* __restrict__ q16, u16* __restrict__ k16,
                                                 float* __restrict__ kc,
                                                 const float* __restrict__ cosb, const float* __restrict__ sinb) {
    int wave = threadIdx.x >> 6, lane = threadIdx.x & 63;
    int idx = blockIdx.x * 4 + wave;
    int t = idx >> 4, h = idx & 15;
    int d = lane & 31;
    float cs = cosb[t * 32 + d];
    float sn = sinb[t * 32 + d];
    size_t b3 = (size_t)t * 3072 + h * HDIM;
    size_t b1 = (size_t)t * CDIM + h * HDIM;

    float xq = qkv[b3 + lane];
    float oq = __shfl(xq, lane ^ 32);
    float rq = (lane < 32) ? fmaf(xq, cs, oq * sn) : fmaf(xq, cs, -oq * sn);
    float ssq = rq * rq;
#pragma unroll
    for (int m = 1; m < 64; m <<= 1) ssq += __shfl_xor(ssq, m);
    rq *= rsqrtf(ssq * (1.f / 64.f) + 1e-6f);
    q16[b1 + lane] = f2h(rq);

    float xk = qkv[b3 + 1024 + lane];
    float ok = __shfl(xk, lane ^ 32);
    float rk = (lane < 32) ? fmaf(xk, cs, ok * sn) : fmaf(xk, cs, -ok * sn);
    float ssk = rk * rk;
#pragma unroll
    for (int m = 1; m < 64; m <<= 1) ssk += __shfl_xor(ssk, m);
    rk *= rsqrtf(ssk * (1.f / 64.f) + 1e-6f);
    k16[b1 + lane] = f2h(rk);

    float s8 = rk * rk;
    s8 += __shfl_xor(s8, 1); s8 += __shfl_xor(s8, 2); s8 += __shfl_xor(s8, 4);
    float sc2 = 1.f / fmaxf(sqrtf(s8), 1e-12f);
    float kcv = rk * sc2;
    if (lane & 7) kcv = -kcv;  // octonion conjugate
    kc[b1 + lane] = kcv;
}

// Causal softmax over packed row (h,i): valid j<=i, zero-fill to ld.
__global__ __launch_bounds__(256) void softmax_rows(u16* __restrict__ S) {
    int wave = threadIdx.x >> 6, lane = threadIdx.x & 63;
    int idx = blockIdx.x * 4 + wave;
    int h = idx >> 11, i = idx & 2047;
    int rb = i >> 7, ld = (rb + 1) * 128;
    u16* row = S + (size_t)h * S_HSTR + (size_t)(rb * (rb + 1) / 2) * 16384 + (size_t)(i & 127) * ld;
    int n = i + 1;
    float m = -1e30f;
    for (int j = lane; j < n; j += 64) m = fmaxf(m, h2f(row[j]));
#pragma unroll
    for (int d = 1; d < 64; d <<= 1) m = fmaxf(m, __shfl_xor(m, d));
    float s = 0.f;
    for (int j = lane; j < n; j += 64) s += __expf(h2f(row[j]) - m);
#pragma unroll
    for (int d = 1; d < 64; d <<= 1) s += __shfl_xor(s, d);
    float inv = 1.f / s;
    for (int j = lane; j < ld; j += 64) {
        float p = (j < n) ? __expf(h2f(row[j]) - m) * inv : 0.f;
        row[j] = f2h(p);
    }
}

// W[h][n=(m*64+a*8+e)][j] from kc (fp32, ld 1024) and v inside qkv (fp32, ld 3072, +2048)
__global__ __launch_bounds__(256) void w_pre(const float* __restrict__ kc, const float* __restrict__ qkv,
                                             u16* __restrict__ W) {
    __shared__ float kcs[64][65];
    __shared__ float vs[64][65];
    int h = blockIdx.y;
    int j0 = blockIdx.x * 64;
    int t = threadIdx.x;
    int r = t >> 2, cq = (t & 3) * 16;
    const float* kp = kc + (size_t)(j0 + r) * CDIM + h * HDIM + cq;
    const float* vp = qkv + (size_t)(j0 + r) * 3072 + 2048 + h * HDIM + cq;
#pragma unroll
    for (int u4 = 0; u4 < 4; ++u4) {
        float4 a = *(const float4*)(kp + u4 * 4);
        float4 b = *(const float4*)(vp + u4 * 4);
        kcs[r][cq + u4 * 4 + 0] = a.x; kcs[r][cq + u4 * 4 + 1] = a.y;
        kcs[r][cq + u4 * 4 + 2] = a.z; kcs[r][cq + u4 * 4 + 3] = a.w;
        vs[r][cq + u4 * 4 + 0] = b.x; vs[r][cq + u4 * 4 + 1] = b.y;
        vs[r][cq + u4 * 4 + 2] = b.z; vs[r][cq + u4 * 4 + 3] = b.w;
    }
    __syncthreads();
    int j = t & 63, g = t >> 6;
    u16* Wp = W + (size_t)h * W_HSTR + j0 + j;
    for (int ae = g * 16; ae < g * 16 + 16; ++ae) {
        int a = ae >> 3, e = ae & 7;
        u32 mask = 0;
#pragma unroll
        for (int qq = 0; qq < 8; ++qq) {
            int p = a ^ e ^ qq;
            u32 bit = (u32)(((SGBITS >> (a * 8 + p)) ^ (SGBITS >> ((e ^ qq) * 8 + qq))) & 1ULL);
            mask |= bit << qq;
        }
#pragma unroll
        for (int m = 0; m < 8; ++m) {
            float w = 0.f;
#pragma unroll
            for (int qq = 0; qq < 8; ++qq) {
                float t1 = kcs[j][m * 8 + (a ^ e ^ qq)] * vs[j][m * 8 + qq];
                w = ((mask >> qq) & 1) ? (w - t1) : (w + t1);
            }
            Wp[(size_t)(m * 64 + ae) * T_SEQ] = f2h(w);
        }
    }
}

// y16[i, h*64+m*8+e] = sum_a q16[i, h*64+m*8+a] * Z[h][i][m*64+a*8+e]
__global__ __launch_bounds__(256) void contract_y(const u16* __restrict__ q16, const u16* __restrict__ Z,
                                                  u16* __restrict__ y16) {
    int wave = threadIdx.x >> 6, lane = threadIdx.x & 63;
    int idx = blockIdx.x * 4 + wave;
    int i = idx >> 4, h = idx & 15;
    int m = lane >> 3, e = lane & 7;
    const u16* qp = q16 + (size_t)i * CDIM + h * HDIM + m * 8;
    uint4 qb = *(const uint4*)qp;
    float qv[8];
    qv[0] = h2f(qb.x & 0xffff); qv[1] = h2f(qb.x >> 16);
    qv[2] = h2f(qb.y & 0xffff); qv[3] = h2f(qb.y >> 16);
    qv[4] = h2f(qb.z & 0xffff); qv[5] = h2f(qb.z >> 16);
    qv[6] = h2f(qb.w & 0xffff); qv[7] = h2f(qb.w >> 16);
    const u16* Zp = Z + (size_t)h * Z_HSTR + (size_t)i * 512 + m * 64 + e;
    float acc = 0.f;
#pragma unroll
    for (int a = 0; a < 8; ++a) acc = fmaf(qv[a], h2f(Zp[a * 8]), acc);
    y16[(size_t)i * CDIM + h * HDIM + lane] = f2h(acc);
}

extern "C" void kernel_launch(void* const* d_in, const int* in_sizes, int n_in,
                              void* d_out, int out_size, void* d_ws, size_t ws_size,
                              hipStream_t stream) {
    const float* x = (const float*)d_in[0];
    const float* cosb = (const float*)d_in[1];
    const float* sinb = (const float*)d_in[2];
    const float* Wq = (const float*)d_in[3];
    const float* Wk = (const float*)d_in[4];
    const float* Wv = (const float*)d_in[5];
    const float* Wo = (const float*)d_in[6];
    float* out = (float*)d_out;
    char* base = (char*)d_ws;
    // workspace layout (197.1 MB total; ws >= 243.3 MB proven in round 4)
    float* qkv = (float*)base;                    // 2048x3072 fp32   25,165,824 B
    float* kc = (float*)(base + 25165824);        // 2048x1024 fp32    8,388,608
    u16* x16 = (u16*)(base + 33554432);           // 2048x1024 fp16    4,194,304
    u16* w16 = (u16*)(base + 37748736);           // 4x 1024x1024 fp16 8,388,608
    u16* q16 = (u16*)(base + 46137344);           //                   4,194,304
    u16* k16 = (u16*)(base + 50331648);           //                   4,194,304
    u16* y16 = (u16*)(base + 54525952);           //                   4,194,304
    u16* S = (u16*)(base + 58720256);             // packed causal    71,303,168
    u16* W = (u16*)(base + 130023424);            //                  33,554,432
    u16* Z = (u16*)(base + 163577856);            //                  33,554,432

    cvt5<<<dim3(1024, 5), 256, 0, stream>>>(x, Wq, Wk, Wv, Wo, x16, w16);
    // fused QKV projection: qkv[i, 0:3072] = x @ [Wq|Wk|Wv]^T
    hgemm_f32<<<dim3(24, 16), 256, 0, stream>>>(x16, CDIM, w16, CDIM, qkv, 3072, CDIM);
    prep_rope<<<T_SEQ * NHEAD / 4, 256, 0, stream>>>(qkv, q16, k16, kc, cosb, sinb);
    hgemm_qk<<<dim3(16, 16, 16), 256, 0, stream>>>(q16, k16, S);
    softmax_rows<<<NHEAD * T_SEQ / 4, 256, 0, stream>>>(S);
    w_pre<<<dim3(32, 16), 256, 0, stream>>>(kc, qkv, W);
    hgemm_pw<<<1024, 256, 0, stream>>>(S, W, Z);
    contract_y<<<NHEAD * T_SEQ / 4, 256, 0, stream>>>(q16, Z, y16);
    // out = y @ Wo^T
    hgemm_f32<<<dim3(8, 16), 256, 0, stream>>>(y16, CDIM, w16 + 3145728, CDIM, out, CDIM, CDIM);
}

// Round 7
// 306.222 us; speedup vs baseline: 18.0364x; 1.1703x over previous
//
#include <hip/hip_runtime.h>

typedef unsigned short u16;
typedef unsigned int u32;

#define T_SEQ 2048
#define NHEAD 16
#define HDIM 64
#define CDIM 1024
#define W_HSTR (512*2048)
#define Z_HSTR (2048*512)

// Octonion sign table: SG[a][n] = sign of component (a^n) of e_a * e_n.
// Byte a holds row a; bit n set => negative. (Validated end-to-end rounds 3-6.)
#define SGBITS 0xB2D8741EACC66A00ULL

typedef _Float16 f16x8 __attribute__((ext_vector_type(8)));
typedef float f32x4 __attribute__((ext_vector_type(4)));

__device__ __forceinline__ float h2f(u16 u) { _Float16 h; __builtin_memcpy(&h, &u, 2); return (float)h; }
__device__ __forceinline__ u16 f2h(float f) { _Float16 h = (_Float16)f; u16 u; __builtin_memcpy(&u, &h, 2); return u; }
__device__ __forceinline__ u32 pk(float a, float b) { return (u32)f2h(a) | ((u32)f2h(b) << 16); }

// async 16B/lane global->LDS DMA; lds dest wave-uniform (HW adds lane*16)
__device__ __forceinline__ void gload16(const u16* g, u16* l) {
    __builtin_amdgcn_global_load_lds((const __attribute__((address_space(1))) u32*)g,
                                     (__attribute__((address_space(3))) u32*)l, 16, 0, 0);
}

// ---- MFMA tile core (round-6, conflict-free fragment-major LDS) ----
template<bool F16OUT>
__device__ __forceinline__ void hgemm_tile(const u16* __restrict__ At, int lda,
                                           const u16* __restrict__ Bt, int ldb, int K,
                                           float* __restrict__ Cf, u16* __restrict__ Ch,
                                           int ldc, float scale, u16* As, u16* Bs) {
    int t = threadIdx.x;
    int wave = t >> 6, l = t & 63;
    int wm = wave & 1, wn = wave >> 1;
    int quad = l >> 4, lr = l & 15;
    f32x4 acc[4][4];
#pragma unroll
    for (int i = 0; i < 4; ++i)
#pragma unroll
        for (int j = 0; j < 4; ++j) acc[i][j] = (f32x4){0.f, 0.f, 0.f, 0.f};
    int acol = quad * 8;
    for (int k0 = 0; k0 < K; k0 += 64) {
#pragma unroll
        for (int j = 0; j < 4; ++j) {
            int d = wave * 4 + j;
            int kb = d >> 3, seg = d & 7;
            size_t roff = (size_t)(seg * 16 + lr);
            int coff = k0 + kb * 32 + acol;
            gload16(At + roff * lda + coff, As + d * 512);
            gload16(Bt + roff * ldb + coff, Bs + d * 512);
        }
        __syncthreads();
#pragma unroll
        for (int kb = 0; kb < 2; ++kb) {
            f16x8 af[4], bf[4];
#pragma unroll
            for (int mi = 0; mi < 4; ++mi) af[mi] = *(const f16x8*)&As[(kb * 8 + wm * 4 + mi) * 512 + l * 8];
#pragma unroll
            for (int ni = 0; ni < 4; ++ni) bf[ni] = *(const f16x8*)&Bs[(kb * 8 + wn * 4 + ni) * 512 + l * 8];
#pragma unroll
            for (int mi = 0; mi < 4; ++mi)
#pragma unroll
                for (int ni = 0; ni < 4; ++ni)
                    acc[mi][ni] = __builtin_amdgcn_mfma_f32_16x16x32_f16(af[mi], bf[ni], acc[mi][ni], 0, 0, 0);
        }
        __syncthreads();
    }
#pragma unroll
    for (int mi = 0; mi < 4; ++mi)
#pragma unroll
        for (int ni = 0; ni < 4; ++ni)
#pragma unroll
            for (int rr = 0; rr < 4; ++rr) {
                int gr = wm * 64 + mi * 16 + quad * 4 + rr;
                int gc = wn * 64 + ni * 16 + lr;
                float v = acc[mi][ni][rr] * scale;
                if (F16OUT) Ch[(size_t)gr * ldc + gc] = f2h(v);
                else Cf[(size_t)gr * ldc + gc] = v;
            }
}

__global__ __launch_bounds__(256) void hgemm_f32(const u16* __restrict__ A, int lda,
                                                 const u16* __restrict__ B, int ldb,
                                                 float* __restrict__ C, int ldc, int K) {
    __shared__ u16 As[8192], Bs[8192];
    int bm = blockIdx.y * 128, bn = blockIdx.x * 128;
    hgemm_tile<false>(A + (size_t)bm * lda, lda, B + (size_t)bn * ldb, ldb, K,
                      C + (size_t)bm * ldc + bn, nullptr, ldc, 1.f, As, Bs);
}

// ---- fused causal attention core: S=QK^T -> p=exp (no-max: |s|<=8) -> Z=P.W, l=P.1 ----
// block = (rb desc LPT, h xcd-pinned, n-quarter). P round-trips through LDS (C->A layout).
__global__ __launch_bounds__(256, 2) void flash_pw(const u16* __restrict__ q16,
                                                   const u16* __restrict__ k16,
                                                   const u16* __restrict__ W,
                                                   u16* __restrict__ Z) {
    __shared__ u16 Pl[128 * 136];
    int idx = blockIdx.x;
    int rb = 15 - (idx >> 6);
    int i6 = idx & 63;
    int h = ((i6 & 7) << 1) | ((i6 >> 3) & 1);  // same-h blocks share an XCD (L2 W-locality)
    int nq = i6 >> 4;
    int t = threadIdx.x;
    int wave = t >> 6, l = t & 63;
    int wm = wave & 1, wn = wave >> 1;
    int quad = l >> 4, lr = l & 15;

    // Q A-frags persist in registers (A[m=lane&15][k=quad*8+j])
    const u16* qbase = q16 + (size_t)(rb * 128 + wm * 64 + lr) * CDIM + h * HDIM + quad * 8;
    f16x8 qa[4][2];
#pragma unroll
    for (int mi = 0; mi < 4; ++mi)
#pragma unroll
        for (int kb = 0; kb < 2; ++kb)
            qa[mi][kb] = *(const f16x8*)(qbase + (size_t)(mi * 16) * CDIM + kb * 32);

    f32x4 accz[4][4];
    f32x4 accl[4];
#pragma unroll
    for (int mi = 0; mi < 4; ++mi) {
        accl[mi] = (f32x4){0.f, 0.f, 0.f, 0.f};
#pragma unroll
        for (int ni = 0; ni < 4; ++ni) accz[mi][ni] = (f32x4){0.f, 0.f, 0.f, 0.f};
    }
    f16x8 ones;
#pragma unroll
    for (int j = 0; j < 8; ++j) ones[j] = (_Float16)1.0f;

    const u16* kbase = k16 + (size_t)(wn * 64 + lr) * CDIM + h * HDIM + quad * 8;
    const u16* Wbase = W + (size_t)h * W_HSTR + (size_t)(nq * 128 + wn * 64 + lr) * T_SEQ + quad * 8;

    for (int cb = 0; cb <= rb; ++cb) {
        f16x8 kf[4][2];
#pragma unroll
        for (int ni = 0; ni < 4; ++ni)
#pragma unroll
            for (int kb = 0; kb < 2; ++kb)
                kf[ni][kb] = *(const f16x8*)(kbase + (size_t)(cb * 128 + ni * 16) * CDIM + kb * 32);
        f32x4 s[4][4];
#pragma unroll
        for (int mi = 0; mi < 4; ++mi)
#pragma unroll
            for (int ni = 0; ni < 4; ++ni) s[mi][ni] = (f32x4){0.f, 0.f, 0.f, 0.f};
#pragma unroll
        for (int kb = 0; kb < 2; ++kb)
#pragma unroll
            for (int mi = 0; mi < 4; ++mi)
#pragma unroll
                for (int ni = 0; ni < 4; ++ni)
                    s[mi][ni] = __builtin_amdgcn_mfma_f32_16x16x32_f16(qa[mi][kb], kf[ni][kb], s[mi][ni], 0, 0, 0);
        // p = exp(s*0.125), causal mask on diagonal tile; write P to LDS (C-layout scatter)
#pragma unroll
        for (int mi = 0; mi < 4; ++mi) {
            int row = wm * 64 + mi * 16 + quad * 4;
#pragma unroll
            for (int ni = 0; ni < 4; ++ni) {
                int col = wn * 64 + ni * 16 + lr;
#pragma unroll
                for (int rr = 0; rr < 4; ++rr) {
                    bool valid = (cb < rb) | (col <= row + rr);
                    float p = valid ? __expf(s[mi][ni][rr] * 0.125f) : 0.f;
                    Pl[(row + rr) * 136 + col] = f2h(p);
                }
            }
        }
        __syncthreads();
        // Z += P*W^T, l += P*1 ; W B-frags straight from global (L2-resident slab)
#pragma unroll
        for (int kb = 0; kb < 4; ++kb) {
            f16x8 pf[4], wf[4];
#pragma unroll
            for (int ni = 0; ni < 4; ++ni)
                wf[ni] = *(const f16x8*)(Wbase + (size_t)(ni * 16) * T_SEQ + cb * 128 + kb * 32);
#pragma unroll
            for (int mi = 0; mi < 4; ++mi)
                pf[mi] = *(const f16x8*)&Pl[(wm * 64 + mi * 16 + lr) * 136 + kb * 32 + quad * 8];
#pragma unroll
            for (int mi = 0; mi < 4; ++mi) {
#pragma unroll
                for (int ni = 0; ni < 4; ++ni)
                    accz[mi][ni] = __builtin_amdgcn_mfma_f32_16x16x32_f16(pf[mi], wf[ni], accz[mi][ni], 0, 0, 0);
                accl[mi] = __builtin_amdgcn_mfma_f32_16x16x32_f16(pf[mi], ones, accl[mi], 0, 0, 0);
            }
        }
        __syncthreads();
    }
    u16* Zb = Z + (size_t)h * Z_HSTR;
#pragma unroll
    for (int mi = 0; mi < 4; ++mi)
#pragma unroll
        for (int rr = 0; rr < 4; ++rr) {
            int row = rb * 128 + wm * 64 + mi * 16 + quad * 4 + rr;
            float inv = 1.f / accl[mi][rr];
#pragma unroll
            for (int ni = 0; ni < 4; ++ni) {
                int col = nq * 128 + wn * 64 + ni * 16 + lr;
                Zb[(size_t)row * 512 + col] = f2h(accz[mi][ni][rr] * inv);
            }
        }
}

// fp32 -> fp16 conversions: z=0 x(2M), z=1..4 Wq/Wk/Wv/Wo (1M each) into w16
__global__ __launch_bounds__(256) void cvt5(const float* __restrict__ x, const float* __restrict__ wq,
                                            const float* __restrict__ wk, const float* __restrict__ wv,
                                            const float* __restrict__ wo,
                                            u16* __restrict__ x16, u16* __restrict__ w16) {
    int z = blockIdx.y;
    size_t base = ((size_t)blockIdx.x * 256 + threadIdx.x) * 8;
    const float* src;
    u16* dst;
    size_t cnt;
    if (z == 0) { src = x; dst = x16; cnt = 2097152; }
    else if (z == 1) { src = wq; dst = w16; cnt = 1048576; }
    else if (z == 2) { src = wk; dst = w16 + 1048576; cnt = 1048576; }
    else if (z == 3) { src = wv; dst = w16 + 2097152; cnt = 1048576; }
    else { src = wo; dst = w16 + 3145728; cnt = 1048576; }
    if (base >= cnt) return;
    float4 f0 = *(const float4*)(src + base);
    float4 f1 = *(const float4*)(src + base + 4);
    uint4 o;
    o.x = pk(f0.x, f0.y); o.y = pk(f0.z, f0.w); o.z = pk(f1.x, f1.y); o.w = pk(f1.z, f1.w);
    *(uint4*)(dst + base) = o;
}

// One wave per (t,h): rotary+RMS for q,k from fused qkv (ld 3072); writes q16,k16 (fp16), kc (fp32).
__global__ __launch_bounds__(256) void prep_rope(const float* __restrict__ qkv,
                                                 u16* __restrict__ q16, u16* __restrict__ k16,
                                                 float* __restrict__ kc,
                                                 const float* __restrict__ cosb, const float* __restrict__ sinb) {
    int wave = threadIdx.x >> 6, lane = threadIdx.x & 63;
    int idx = blockIdx.x * 4 + wave;
    int t = idx >> 4, h = idx & 15;
    int d = lane & 31;
    float cs = cosb[t * 32 + d];
    float sn = sinb[t * 32 + d];
    size_t b3 = (size_t)t * 3072 + h * HDIM;
    size_t b1 = (size_t)t * CDIM + h * HDIM;

    float xq = qkv[b3 + lane];
    float oq = __shfl(xq, lane ^ 32);
    float rq = (lane < 32) ? fmaf(xq, cs, oq * sn) : fmaf(xq, cs, -oq * sn);
    float ssq = rq * rq;
#pragma unroll
    for (int m = 1; m < 64; m <<= 1) ssq += __shfl_xor(ssq, m);
    rq *= rsqrtf(ssq * (1.f / 64.f) + 1e-6f);
    q16[b1 + lane] = f2h(rq);

    float xk = qkv[b3 + 1024 + lane];
    float ok = __shfl(xk, lane ^ 32);
    float rk = (lane < 32) ? fmaf(xk, cs, ok * sn) : fmaf(xk, cs, -ok * sn);
    float ssk = rk * rk;
#pragma unroll
    for (int m = 1; m < 64; m <<= 1) ssk += __shfl_xor(ssk, m);
    rk *= rsqrtf(ssk * (1.f / 64.f) + 1e-6f);
    k16[b1 + lane] = f2h(rk);

    float s8 = rk * rk;
    s8 += __shfl_xor(s8, 1); s8 += __shfl_xor(s8, 2); s8 += __shfl_xor(s8, 4);
    float sc2 = 1.f / fmaxf(sqrtf(s8), 1e-12f);
    float kcv = rk * sc2;
    if (lane & 7) kcv = -kcv;  // octonion conjugate
    kc[b1 + lane] = kcv;
}

// W[h][n=(m*64+a*8+e)][j] from kc (fp32, ld 1024) and v inside qkv (fp32, ld 3072, +2048)
__global__ __launch_bounds__(256) void w_pre(const float* __restrict__ kc, const float* __restrict__ qkv,
                                             u16* __restrict__ W) {
    __shared__ float kcs[64][65];
    __shared__ float vs[64][65];
    int h = blockIdx.y;
    int j0 = blockIdx.x * 64;
    int t = threadIdx.x;
    int r = t >> 2, cq = (t & 3) * 16;
    const float* kp = kc + (size_t)(j0 + r) * CDIM + h * HDIM + cq;
    const float* vp = qkv + (size_t)(j0 + r) * 3072 + 2048 + h * HDIM + cq;
#pragma unroll
    for (int u4 = 0; u4 < 4; ++u4) {
        float4 a = *(const float4*)(kp + u4 * 4);
        float4 b = *(const float4*)(vp + u4 * 4);
        kcs[r][cq + u4 * 4 + 0] = a.x; kcs[r][cq + u4 * 4 + 1] = a.y;
        kcs[r][cq + u4 * 4 + 2] = a.z; kcs[r][cq + u4 * 4 + 3] = a.w;
        vs[r][cq + u4 * 4 + 0] = b.x; vs[r][cq + u4 * 4 + 1] = b.y;
        vs[r][cq + u4 * 4 + 2] = b.z; vs[r][cq + u4 * 4 + 3] = b.w;
    }
    __syncthreads();
    int j = t & 63, g = t >> 6;
    u16* Wp = W + (size_t)h * W_HSTR + j0 + j;
    for (int ae = g * 16; ae < g * 16 + 16; ++ae) {
        int a = ae >> 3, e = ae & 7;
        u32 mask = 0;
#pragma unroll
        for (int qq = 0; qq < 8; ++qq) {
            int p = a ^ e ^ qq;
            u32 bit = (u32)(((SGBITS >> (a * 8 + p)) ^ (SGBITS >> ((e ^ qq) * 8 + qq))) & 1ULL);
            mask |= bit << qq;
        }
#pragma unroll
        for (int m = 0; m < 8; ++m) {
            float w = 0.f;
#pragma unroll
            for (int qq = 0; qq < 8; ++qq) {
                float t1 = kcs[j][m * 8 + (a ^ e ^ qq)] * vs[j][m * 8 + qq];
                w = ((mask >> qq) & 1) ? (w - t1) : (w + t1);
            }
            Wp[(size_t)(m * 64 + ae) * T_SEQ] = f2h(w);
        }
    }
}

// y16[i, h*64+m*8+e] = sum_a q16[..m*8+a] * Z[h][i][m*64+a*8+e]; Z row staged via LDS (coalesced)
__global__ __launch_bounds__(256) void contract_y(const u16* __restrict__ q16, const u16* __restrict__ Z,
                                                  u16* __restrict__ y16) {
    __shared__ u16 zb[4][512];
    int wave = threadIdx.x >> 6, lane = threadIdx.x & 63;
    int idx = blockIdx.x * 4 + wave;
    int i = idx >> 4, h = idx & 15;
    uint4 zv = *(const uint4*)(Z + (size_t)h * Z_HSTR + (size_t)i * 512 + lane * 8);
    *(uint4*)&zb[wave][lane * 8] = zv;
    int m = lane >> 3, e = lane & 7;
    const u16* qp = q16 + (size_t)i * CDIM + h * HDIM + m * 8;
    uint4 qb = *(const uint4*)qp;
    float qv[8];
    qv[0] = h2f(qb.x & 0xffff); qv[1] = h2f(qb.x >> 16);
    qv[2] = h2f(qb.y & 0xffff); qv[3] = h2f(qb.y >> 16);
    qv[4] = h2f(qb.z & 0xffff); qv[5] = h2f(qb.z >> 16);
    qv[6] = h2f(qb.w & 0xffff); qv[7] = h2f(qb.w >> 16);
    __syncthreads();
    float acc = 0.f;
#pragma unroll
    for (int a = 0; a < 8; ++a) acc = fmaf(qv[a], h2f(zb[wave][m * 64 + a * 8 + e]), acc);
    y16[(size_t)i * CDIM + h * HDIM + lane] = f2h(acc);
}

extern "C" void kernel_launch(void* const* d_in, const int* in_sizes, int n_in,
                              void* d_out, int out_size, void* d_ws, size_t ws_size,
                              hipStream_t stream) {
    const float* x = (const float*)d_in[0];
    const float* cosb = (const float*)d_in[1];
    const float* sinb = (const float*)d_in[2];
    const float* Wq = (const float*)d_in[3];
    const float* Wk = (const float*)d_in[4];
    const float* Wv = (const float*)d_in[5];
    const float* Wo = (const float*)d_in[6];
    float* out = (float*)d_out;
    char* base = (char*)d_ws;
    // workspace layout (~126 MB total; ws >= 243 MB proven)
    float* qkv = (float*)base;                    // 2048x3072 fp32   25,165,824 B
    float* kc = (float*)(base + 25165824);        // 2048x1024 fp32    8,388,608
    u16* x16 = (u16*)(base + 33554432);           //                   4,194,304
    u16* w16 = (u16*)(base + 37748736);           // 4x 1024x1024 fp16 8,388,608
    u16* q16 = (u16*)(base + 46137344);           //                   4,194,304
    u16* k16 = (u16*)(base + 50331648);           //                   4,194,304
    u16* y16 = (u16*)(base + 54525952);           //                   4,194,304
    u16* W = (u16*)(base + 58720256);             //                  33,554,432
    u16* Z = (u16*)(base + 92274688);             //                  33,554,432

    cvt5<<<dim3(1024, 5), 256, 0, stream>>>(x, Wq, Wk, Wv, Wo, x16, w16);
    hgemm_f32<<<dim3(24, 16), 256, 0, stream>>>(x16, CDIM, w16, CDIM, qkv, 3072, CDIM);
    prep_rope<<<T_SEQ * NHEAD / 4, 256, 0, stream>>>(qkv, q16, k16, kc, cosb, sinb);
    w_pre<<<dim3(32, 16), 256, 0, stream>>>(kc, qkv, W);
    flash_pw<<<1024, 256, 0, stream>>>(q16, k16, W, Z);
    contract_y<<<NHEAD * T_SEQ / 4, 256, 0, stream>>>(q16, Z, y16);
    hgemm_f32<<<dim3(8, 16), 256, 0, stream>>>(y16, CDIM, w16 + 3145728, CDIM, out, CDIM, CDIM);
}